// Round 8
// baseline (624.935 us; speedup 1.0000x reference)
//
#include <hip/hip_runtime.h>

#define T_STEPS 512
#define IN_DIM 11
#define ROW_PAD 12
#define H_DIM 16
#define G_DIM 64
#define ROW_F (T_STEPS * IN_DIM)
#define CHUNK_T 16
#define CHUNK_F (CHUNK_T * IN_DIM)
#define N_CHUNK (T_STEPS / CHUNK_T)
#define LOG2E 1.44269504088896340736f
#define XG_BYTES ((size_t)4096 * T_STEPS * G_DIM * 2)

typedef _Float16 v2h __attribute__((ext_vector_type(2)));
typedef _Float16 v4h __attribute__((ext_vector_type(4)));
typedef _Float16 v8h __attribute__((ext_vector_type(8)));

__device__ __forceinline__ float fdot2(v2h a, v2h b, float c) {
    return __builtin_amdgcn_fdot2(a, b, c, false);
}

template<int CTRL>
__device__ __forceinline__ float qperm(float v) {
    return __builtin_bit_cast(float,
        __builtin_amdgcn_update_dpp(0, __builtin_bit_cast(int, v),
                                    CTRL, 0xf, 0xf, true));
}

__device__ __forceinline__ float bcast_lane(float v, int l) {
    return __builtin_bit_cast(float,
        __builtin_amdgcn_readlane(__builtin_bit_cast(int, v), l));
}

__device__ __forceinline__ v2h pair_lo(v8h v, int) { return (v2h){v[0], v[1]}; }

// ---------------------------------------------------------------------------
// Pre-kernel: xg[b][t][l] = M(l) * (Wih1[row(l)] . x[b][t] + bih1 + bhh1),
// stored f16 in lane order l = 4*r + gate (matches main kernel's lane map).
// One block per batch b; 4 waves x 128 t each. x row address is wave-uniform
// -> scalar loads; weights per-lane in VGPRs, loaded once.
// ---------------------------------------------------------------------------
__global__ __launch_bounds__(256) void xg_pre(
    const float* __restrict__ x,
    const float* __restrict__ Wih1,
    const float* __restrict__ bih1, const float* __restrict__ bhh1,
    _Float16* __restrict__ xg)
{
    const int lane = threadIdx.x & 63;
    const int wid = __builtin_amdgcn_readfirstlane((int)(threadIdx.x >> 6));
    const int b = blockIdx.x;

    const int r   = lane >> 2;
    const int gt  = lane & 3;
    const int row = gt * H_DIM + r;
    const float M = (gt == 2) ? (-2.0f * LOG2E) : (-LOG2E);

    float wi[IN_DIM];
    #pragma unroll
    for (int k = 0; k < IN_DIM; ++k) wi[k] = M * Wih1[row * IN_DIM + k];
    const float binit = M * (bih1[row] + bhh1[row]);

    const float* __restrict__ xb = x + (size_t)b * ROW_F;
    _Float16* __restrict__ og = xg + ((size_t)b * T_STEPS) * G_DIM;

    for (int t = wid * 128; t < wid * 128 + 128; ++t) {
        const float* __restrict__ xr = xb + t * IN_DIM;   // uniform -> s_load
        float acc = binit;
        #pragma unroll
        for (int k = 0; k < IN_DIM; ++k)
            acc = __builtin_fmaf(wi[k], xr[k], acc);
        og[(size_t)t * G_DIM + lane] = (_Float16)acc;     // coalesced b16
    }
}

// ---------------------------------------------------------------------------
// Main kernel. One wave per batch element; lane = 4*r + gate (i,f,g,o quads).
// R8: (1) layer-1 x-contribution precomputed (XG path) -> 24 fdot2/step;
// (2) g-gate activation pre-scaled by -2*log2e so the cell state is carried
// as c' = -2L*c and tanh(c) = 2*rcp(1+exp2(c'))-1 with no pre-multiply;
// (3) h read-back as 2x ds_read_b128. h broadcast stays on the LDS path
// (R7 proved the readlane path costs more VALU issue than LDS costs stalls).
// ---------------------------------------------------------------------------
template<bool XG>
__global__ __launch_bounds__(256)
__attribute__((amdgpu_waves_per_eu(4, 4)))
void lstm2_head(
    const float* __restrict__ x, const _Float16* __restrict__ xg,
    const float* __restrict__ Wih1, const float* __restrict__ Whh1,
    const float* __restrict__ bih1, const float* __restrict__ bhh1,
    const float* __restrict__ Wih2, const float* __restrict__ Whh2,
    const float* __restrict__ bih2, const float* __restrict__ bhh2,
    const float* __restrict__ Wd1, const float* __restrict__ bd1,
    const float* __restrict__ Wd2, const float* __restrict__ bd2,
    const float* __restrict__ Wd3, const float* __restrict__ bd3,
    float* __restrict__ out)
{
    // XG path: chunk = 16 t x 64 f16 = 2 KB; fallback: padded f16 x rows.
    __shared__ __align__(16) _Float16 xlds[4][2][XG ? 1024 : 216];
    __shared__ __align__(16) _Float16 hsl[4][2][16];

    const int lane = threadIdx.x & 63;
    const int wid = __builtin_amdgcn_readfirstlane((int)(threadIdx.x >> 6));
    const int b = blockIdx.x * 4 + wid;

    const int r   = lane >> 2;
    const int gt  = lane & 3;
    const int row = gt * H_DIM + r;

    const bool is_t = (gt == 2);
    const float M   = is_t ? (-2.0f * LOG2E) : (-LOG2E);
    // g-lane activation emits -2L*tanh(g) directly: A=-4L, B=+2L.
    const float vAa = is_t ? (-4.0f * LOG2E) : 1.0f;
    const float vBc = is_t ? (2.0f * LOG2E) : 0.0f;

    v2h wi1h[6], wh1h[8], wi2h[8], wh2h[8];
    if (!XG) {
        #pragma unroll
        for (int j = 0; j < 5; ++j)
            wi1h[j] = (v2h){(_Float16)(M * Wih1[row * IN_DIM + 2 * j]),
                            (_Float16)(M * Wih1[row * IN_DIM + 2 * j + 1])};
        wi1h[5] = (v2h){(_Float16)(M * Wih1[row * IN_DIM + 10]), (_Float16)0.0f};
        #pragma unroll
        for (int j = 0; j < 6; ++j) asm volatile("" : "+v"(wi1h[j]));
    }
    #pragma unroll
    for (int j = 0; j < 8; ++j) {
        wh1h[j] = (v2h){(_Float16)(M * Whh1[row * H_DIM + 2 * j]),
                        (_Float16)(M * Whh1[row * H_DIM + 2 * j + 1])};
        wi2h[j] = (v2h){(_Float16)(M * Wih2[row * H_DIM + 2 * j]),
                        (_Float16)(M * Wih2[row * H_DIM + 2 * j + 1])};
        wh2h[j] = (v2h){(_Float16)(M * Whh2[row * H_DIM + 2 * j]),
                        (_Float16)(M * Whh2[row * H_DIM + 2 * j + 1])};
    }
    const float bb1 = XG ? 0.0f : (M * (bih1[row] + bhh1[row]));
    const float bb2 = M * (bih2[row] + bhh2[row]);
    #pragma unroll
    for (int j = 0; j < 8; ++j) {
        asm volatile("" : "+v"(wh1h[j]));
        asm volatile("" : "+v"(wi2h[j]));
        asm volatile("" : "+v"(wh2h[j]));
    }

    _Float16* const xl0 = &xlds[wid][0][0];
    _Float16* const xl1 = &xlds[wid][1][0];
    _Float16* const h1w = &hsl[wid][0][0];
    _Float16* const h2w = &hsl[wid][1][0];

    // init h slabs (per-wave LDS; same-wave ordering, no barrier needed)
    if (lane < 32) hsl[wid][lane >> 4][lane & 15] = (_Float16)0.0f;

    // ---- staging state ----
    const float* __restrict__ xb = x + (size_t)b * ROW_F;
    const uint4* __restrict__ gb4 =
        (const uint4*)(xg + ((size_t)b * T_STEPS) * G_DIM);
    int p1 = 0, p2 = 0, p3 = 0;
    float gl0 = 0.f, gl1 = 0.f, gl2 = 0.f;
    uint4 ga = {}, gb = {};
    if (XG) {
        ga = gb4[lane];
        gb = gb4[64 + lane];
    } else {
        if (lane < 32) {
            const int buf = lane >> 4, rr = lane & 15;
            xlds[wid][buf][rr * ROW_PAD + IN_DIM] = (_Float16)0.0f;
        }
        const int f1i = lane, f2i = lane + 64, f3i = lane + 128;
        p1 = (f1i / IN_DIM) * ROW_PAD + (f1i % IN_DIM);
        p2 = (f2i / IN_DIM) * ROW_PAD + (f2i % IN_DIM);
        p3 = (f3i / IN_DIM) * ROW_PAD + (f3i % IN_DIM);
        gl0 = xb[f1i]; gl1 = xb[f2i]; gl2 = xb[min(f3i, ROW_F - 1)];
    }

    float c1 = 0.f, c2 = 0.f, h2v = 0.f, ssum = 0.f;
    v8h h1a = {}, h1b = {}, h2a = {}, h2b = {};   // h pairs (2x b128 reads)

    #define DOT8(ACC1, ACC2, W, HA, HB)                                        \
        {                                                                      \
            ACC1 = fdot2(W[0], (v2h){HA[0], HA[1]}, ACC1);                     \
            ACC2 = fdot2(W[4], (v2h){HB[0], HB[1]}, ACC2);                     \
            ACC1 = fdot2(W[1], (v2h){HA[2], HA[3]}, ACC1);                     \
            ACC2 = fdot2(W[5], (v2h){HB[2], HB[3]}, ACC2);                     \
            ACC1 = fdot2(W[2], (v2h){HA[4], HA[5]}, ACC1);                     \
            ACC2 = fdot2(W[6], (v2h){HB[4], HB[5]}, ACC2);                     \
            ACC1 = fdot2(W[3], (v2h){HA[6], HA[7]}, ACC1);                     \
            ACC2 = fdot2(W[7], (v2h){HB[6], HB[7]}, ACC2);                     \
        }

    for (int ck = 0; ck < N_CHUNK; ++ck) {
        _Float16* const xbuf = (ck & 1) ? xl1 : xl0;
        if (XG) {
            ((uint4*)xbuf)[lane]      = ga;
            ((uint4*)xbuf)[64 + lane] = gb;
            if (ck + 1 < N_CHUNK) {
                const uint4* np = gb4 + (size_t)(ck + 1) * 128;
                ga = np[lane];
                gb = np[64 + lane];
            }
        } else {
            xbuf[p1] = (_Float16)gl0;
            xbuf[p2] = (_Float16)gl1;
            xbuf[p3] = (_Float16)gl2;
            if (ck + 1 < N_CHUNK) {
                const int base = (ck + 1) * CHUNK_F;
                gl0 = xb[base + lane];
                gl1 = xb[base + lane + 64];
                gl2 = xb[min(base + lane + 128, ROW_F - 1)];
            }
        }

        #pragma unroll
        for (int t2 = 0; t2 < CHUNK_T; ++t2) {
            // ---- layer-2 recurrent dot (reg-resident h2 pairs) ----
            float a2 = bb2, b2 = 0.f;
            DOT8(a2, b2, wh2h, h2a, h2b)

            // ---- layer-1 preact ----
            float a1, b1 = 0.f;
            if (XG) {
                a1 = (float)xbuf[t2 * G_DIM + lane];   // xg = Wih1.x + b (M-scaled)
            } else {
                const v4h* xr4 = (const v4h*)(xbuf + t2 * ROW_PAD);
                const v4h x0 = xr4[0], x1 = xr4[1], x2 = xr4[2];
                a1 = bb1;
                a1 = fdot2(wi1h[0], (v2h){x0[0], x0[1]}, a1);
                b1 = fdot2(wi1h[1], (v2h){x0[2], x0[3]}, b1);
                a1 = fdot2(wi1h[2], (v2h){x1[0], x1[1]}, a1);
                b1 = fdot2(wi1h[3], (v2h){x1[2], x1[3]}, b1);
                a1 = fdot2(wi1h[4], (v2h){x2[0], x2[1]}, a1);
                b1 = fdot2(wi1h[5], (v2h){x2[2], x2[3]}, b1);
            }
            DOT8(a1, b1, wh1h, h1a, h1b)

            // ---- layer 1 activation + cell (c1 carried as -2L*c) ----
            const float g1 = a1 + b1;
            const float act1 = __builtin_fmaf(vAa,
                __builtin_amdgcn_rcpf(1.0f + __builtin_amdgcn_exp2f(g1)), vBc);
            {
                const float gi = qperm<0x00>(act1);
                const float gf = qperm<0x55>(act1);
                const float gg = qperm<0xAA>(act1);   // = -2L*tanh(g)
                const float go = qperm<0xFF>(act1);
                c1 = __builtin_fmaf(gf, c1, gi * gg);
                const float tc = __builtin_fmaf(2.0f,
                    __builtin_amdgcn_rcpf(1.0f + __builtin_amdgcn_exp2f(c1)),
                    -1.0f);
                h1w[r] = (_Float16)(go * tc);         // quad-replicated write
            }
            h1a = ((const v8h*)h1w)[0];
            h1b = ((const v8h*)h1w)[1];

            float xa2 = 0.f;
            DOT8(a2, xa2, wi2h, h1a, h1b)
            b2 += xa2;

            // ---- layer 2 activation + cell ----
            const float g2 = a2 + b2;
            const float act2 = __builtin_fmaf(vAa,
                __builtin_amdgcn_rcpf(1.0f + __builtin_amdgcn_exp2f(g2)), vBc);
            {
                const float gi = qperm<0x00>(act2);
                const float gf = qperm<0x55>(act2);
                const float gg = qperm<0xAA>(act2);
                const float go = qperm<0xFF>(act2);
                c2 = __builtin_fmaf(gf, c2, gi * gg);
                const float tc = __builtin_fmaf(2.0f,
                    __builtin_amdgcn_rcpf(1.0f + __builtin_amdgcn_exp2f(c2)),
                    -1.0f);
                h2v = go * tc;                        // quad-replicated
                h2w[r] = (_Float16)h2v;
            }
            h2a = ((const v8h*)h2w)[0];
            h2b = ((const v8h*)h2w)[1];

            ssum += __builtin_amdgcn_exp2f(LOG2E * h2v);
        }
    }
    #undef DOT8

    // s[b,k] = exp(h2[T-1,k]) / sum_t exp(h2[t,k]); h2v replicated per quad.
    const float sv = __builtin_amdgcn_exp2f(LOG2E * h2v) / ssum;

    float ssb[H_DIM];
    #pragma unroll
    for (int k = 0; k < H_DIM; ++k) ssb[k] = bcast_lane(sv, 4 * k);

    const int r8 = lane & 7;
    float acc1 = bd1[r8];
    #pragma unroll
    for (int k = 0; k < H_DIM; ++k)
        acc1 = __builtin_fmaf(Wd1[r8 * H_DIM + k], ssb[k], acc1);

    float d1s[8];
    #pragma unroll
    for (int j = 0; j < 8; ++j) d1s[j] = bcast_lane(acc1, j);

    float acc2 = bd2[r8];
    #pragma unroll
    for (int k = 0; k < 8; ++k)
        acc2 = __builtin_fmaf(Wd2[r8 * 8 + k], d1s[k], acc2);

    float d2s[8];
    #pragma unroll
    for (int j = 0; j < 8; ++j) d2s[j] = bcast_lane(acc2, j);

    float lg = 0.f;
    if (lane < 3) {
        lg = bd3[lane];
        #pragma unroll
        for (int k = 0; k < 8; ++k)
            lg = __builtin_fmaf(Wd3[lane * 8 + k], d2s[k], lg);
    }
    const float l0 = bcast_lane(lg, 0);
    const float l1 = bcast_lane(lg, 1);
    const float l2 = bcast_lane(lg, 2);
    const float mx = fmaxf(l0, fmaxf(l1, l2));
    const float e0 = __builtin_amdgcn_exp2f(LOG2E * (l0 - mx));
    const float e1 = __builtin_amdgcn_exp2f(LOG2E * (l1 - mx));
    const float e2 = __builtin_amdgcn_exp2f(LOG2E * (l2 - mx));
    const float inv = 1.0f / (e0 + e1 + e2);
    if (lane < 3) {
        const float ev = (lane == 0) ? e0 : ((lane == 1) ? e1 : e2);
        out[b * 3 + lane] = ev * inv;
    }
}

extern "C" void kernel_launch(void* const* d_in, const int* in_sizes, int n_in,
                              void* d_out, int out_size, void* d_ws, size_t ws_size,
                              hipStream_t stream) {
    (void)in_sizes; (void)n_in; (void)out_size;
    const float* x    = (const float*)d_in[0];
    const float* Wih1 = (const float*)d_in[1];
    const float* Whh1 = (const float*)d_in[2];
    const float* bih1 = (const float*)d_in[3];
    const float* bhh1 = (const float*)d_in[4];
    const float* Wih2 = (const float*)d_in[5];
    const float* Whh2 = (const float*)d_in[6];
    const float* bih2 = (const float*)d_in[7];
    const float* bhh2 = (const float*)d_in[8];
    const float* Wd1  = (const float*)d_in[9];
    const float* bd1  = (const float*)d_in[10];
    const float* Wd2  = (const float*)d_in[11];
    const float* bd2  = (const float*)d_in[12];
    const float* Wd3  = (const float*)d_in[13];
    const float* bd3  = (const float*)d_in[14];

    if (ws_size >= XG_BYTES) {
        _Float16* xg = (_Float16*)d_ws;
        xg_pre<<<dim3(4096), dim3(256), 0, stream>>>(x, Wih1, bih1, bhh1, xg);
        lstm2_head<true><<<dim3(4096 / 4), dim3(256), 0, stream>>>(
            x, xg, Wih1, Whh1, bih1, bhh1, Wih2, Whh2, bih2, bhh2,
            Wd1, bd1, Wd2, bd2, Wd3, bd3, (float*)d_out);
    } else {
        lstm2_head<false><<<dim3(4096 / 4), dim3(256), 0, stream>>>(
            x, (const _Float16*)nullptr, Wih1, Whh1, bih1, bhh1,
            Wih2, Whh2, bih2, bhh2,
            Wd1, bd1, Wd2, bd2, Wd3, bd3, (float*)d_out);
    }
}

// Round 9
// 468.464 us; speedup vs baseline: 1.3340x; 1.3340x over previous
//
#include <hip/hip_runtime.h>

#define T_STEPS 512
#define IN_DIM 11
#define ROW_PAD 12                  // x row padded to 12 f16 (24 B, 8-B aligned)
#define H_DIM 16
#define ROW_F (T_STEPS * IN_DIM)    // 5632 floats per batch row
#define CHUNK_T 16                  // t-steps per x chunk
#define CHUNK_F (CHUNK_T * IN_DIM)  // 176 source floats per chunk
#define N_CHUNK (T_STEPS / CHUNK_T)
#define LOG2E 1.44269504088896340736f

typedef _Float16 v2h __attribute__((ext_vector_type(2)));
typedef _Float16 v4h __attribute__((ext_vector_type(4)));
typedef _Float16 v8h __attribute__((ext_vector_type(8)));

// v_dot2_f32_f16: D = a.x*b.x + a.y*b.y + c (f16 products exact in f32).
__device__ __forceinline__ float fdot2(v2h a, v2h b, float c) {
    return __builtin_amdgcn_fdot2(a, b, c, false);
}
// v_pk_fma_f16: packed f16 FMA, full-rate (2 MACs / 2 cyc) -> 2x dot2 MAC rate.
__device__ __forceinline__ v2h pk_fma_h(v2h a, v2h b, v2h c) {
    v2h d;
    asm("v_pk_fma_f16 %0, %1, %2, %3" : "=v"(d) : "v"(a), "v"(b), "v"(c));
    return d;
}
__device__ __forceinline__ v2h pk_add_h(v2h a, v2h b) {
    v2h d;
    asm("v_pk_add_f16 %0, %1, %2" : "=v"(d) : "v"(a), "v"(b));
    return d;
}

// DPP quad_perm broadcast within each group of 4 lanes.
template<int CTRL>
__device__ __forceinline__ float qperm(float v) {
    return __builtin_bit_cast(float,
        __builtin_amdgcn_update_dpp(0, __builtin_bit_cast(int, v),
                                    CTRL, 0xf, 0xf, true));
}

__device__ __forceinline__ float bcast_lane(float v, int l) {
    return __builtin_bit_cast(float,
        __builtin_amdgcn_readlane(__builtin_bit_cast(int, v), l));
}

// dword-j pair slice of a v8h (register alias, no VALU)
#define HS(V, J) ((v2h){(V)[2 * (J)], (V)[2 * (J) + 1]})

// ---------------------------------------------------------------------------
// One wave per batch element; lane = 4*r + gate (i,f,g,o quads).
// R9: single kernel (xg precompute was a net loss: 295 us pre vs 42 us saved).
// Keeps: R6 LDS h-broadcast + f16 weights; R8 g-gate -2L fold (cell carried
// as c' = -2L*c, tanh(c) = 2*rcp(1+exp2(c'))-1) and 2x ds_read_b128 h reads.
// New: the three 16-deep h-dots run on v_pk_fma_f16 (full-rate packed f16,
// 2x the MAC rate of v_dot2) in f16-pair chains, folded to f32 once per
// preact via fdot2 with (1,1). x-dot stays fdot2 (f32 accum, |x| can be ~5).
// ---------------------------------------------------------------------------
__global__ __launch_bounds__(256)
__attribute__((amdgpu_waves_per_eu(4, 4)))
void lstm2_head(
    const float* __restrict__ x,
    const float* __restrict__ Wih1, const float* __restrict__ Whh1,
    const float* __restrict__ bih1, const float* __restrict__ bhh1,
    const float* __restrict__ Wih2, const float* __restrict__ Whh2,
    const float* __restrict__ bih2, const float* __restrict__ bhh2,
    const float* __restrict__ Wd1, const float* __restrict__ bd1,
    const float* __restrict__ Wd2, const float* __restrict__ bd2,
    const float* __restrict__ Wd3, const float* __restrict__ bd3,
    float* __restrict__ out)
{
    __shared__ __align__(16) _Float16 xlds[4][2][216];  // [wave][buf][padded chunk]
    __shared__ __align__(16) _Float16 hsl[4][2][16];    // [wave][layer][h]

    const int lane = threadIdx.x & 63;
    const int wid = __builtin_amdgcn_readfirstlane((int)(threadIdx.x >> 6));
    const int b = blockIdx.x * 4 + wid;

    const int r   = lane >> 2;          // hidden index 0..15
    const int gt  = lane & 3;           // 0:i 1:f 2:g(tanh) 3:o
    const int row = gt * H_DIM + r;     // row in packed 4H weights

    const bool is_t = (gt == 2);
    const float M   = is_t ? (-2.0f * LOG2E) : (-LOG2E);
    // g-lane activation emits -2L*tanh(g) directly: A = -4L, B = +2L.
    const float vAa = is_t ? (-4.0f * LOG2E) : 1.0f;
    const float vBc = is_t ? (2.0f * LOG2E) : 0.0f;

    // ---- per-lane weights, M-scaled, packed f16 pairs (pinned VGPRs) ----
    v2h wi1h[6], wh1h[8], wi2h[8], wh2h[8];
    #pragma unroll
    for (int j = 0; j < 5; ++j)
        wi1h[j] = (v2h){(_Float16)(M * Wih1[row * IN_DIM + 2 * j]),
                        (_Float16)(M * Wih1[row * IN_DIM + 2 * j + 1])};
    wi1h[5] = (v2h){(_Float16)(M * Wih1[row * IN_DIM + 10]), (_Float16)0.0f};
    #pragma unroll
    for (int j = 0; j < 8; ++j) {
        wh1h[j] = (v2h){(_Float16)(M * Whh1[row * H_DIM + 2 * j]),
                        (_Float16)(M * Whh1[row * H_DIM + 2 * j + 1])};
        wi2h[j] = (v2h){(_Float16)(M * Wih2[row * H_DIM + 2 * j]),
                        (_Float16)(M * Wih2[row * H_DIM + 2 * j + 1])};
        wh2h[j] = (v2h){(_Float16)(M * Whh2[row * H_DIM + 2 * j]),
                        (_Float16)(M * Whh2[row * H_DIM + 2 * j + 1])};
    }
    const float bb1 = M * (bih1[row] + bhh1[row]);
    const float bb2 = M * (bih2[row] + bhh2[row]);
    #pragma unroll
    for (int j = 0; j < 6; ++j) asm volatile("" : "+v"(wi1h[j]));
    #pragma unroll
    for (int j = 0; j < 8; ++j) {
        asm volatile("" : "+v"(wh1h[j]));
        asm volatile("" : "+v"(wi2h[j]));
        asm volatile("" : "+v"(wh2h[j]));
    }

    const float* __restrict__ xb = x + (size_t)b * ROW_F;
    _Float16* const xl0 = &xlds[wid][0][0];
    _Float16* const xl1 = &xlds[wid][1][0];
    _Float16* const h1w = &hsl[wid][0][0];
    _Float16* const h2w = &hsl[wid][1][0];

    // init h slabs + x pad slots (per-wave LDS, same-wave order, no barrier)
    if (lane < 32) hsl[wid][lane >> 4][lane & 15] = (_Float16)0.0f;
    if (lane < 32) {
        const int buf = lane >> 4, rr = lane & 15;
        xlds[wid][buf][rr * ROW_PAD + IN_DIM] = (_Float16)0.0f;
    }

    // staging: source float f -> padded f16 slot (f/11)*12 + f%11
    const int f1i = lane, f2i = lane + 64, f3i = lane + 128;
    const int p1 = (f1i / IN_DIM) * ROW_PAD + (f1i % IN_DIM);
    const int p2 = (f2i / IN_DIM) * ROW_PAD + (f2i % IN_DIM);
    const int p3 = (f3i / IN_DIM) * ROW_PAD + (f3i % IN_DIM);

    // prologue: global-load chunk 0
    float gl0 = xb[f1i];
    float gl1 = xb[f2i];
    float gl2 = xb[min(f3i, ROW_F - 1)];

    float c1 = 0.f, c2 = 0.f, h2v = 0.f, ssum = 0.f;
    v8h h1a = {}, h1b = {}, h2a = {}, h2b = {};     // h pairs (2x b128 reads)
    const v2h ones = (v2h){(_Float16)1.0f, (_Float16)1.0f};
    const v2h z2   = (v2h){(_Float16)0.0f, (_Float16)0.0f};

    for (int ck = 0; ck < N_CHUNK; ++ck) {
        _Float16* const xbuf = (ck & 1) ? xl1 : xl0;
        xbuf[p1] = (_Float16)gl0;
        xbuf[p2] = (_Float16)gl1;
        xbuf[p3] = (_Float16)gl2;
        if (ck + 1 < N_CHUNK) {
            const int base = (ck + 1) * CHUNK_F;
            gl0 = xb[base + f1i];
            gl1 = xb[base + f2i];
            gl2 = xb[min(base + f3i, ROW_F - 1)];
        }

        #pragma unroll
        for (int t2 = 0; t2 < CHUNK_T; ++t2) {
            // ---- layer-2 recurrent partial: wh2 . h2(t-1), f16-pair chains ----
            v2h p0 = pk_fma_h(wh2h[0], HS(h2a, 0), z2);
            v2h q0 = pk_fma_h(wh2h[4], HS(h2b, 0), z2);
            p0 = pk_fma_h(wh2h[1], HS(h2a, 1), p0);
            q0 = pk_fma_h(wh2h[5], HS(h2b, 1), q0);
            p0 = pk_fma_h(wh2h[2], HS(h2a, 2), p0);
            q0 = pk_fma_h(wh2h[6], HS(h2b, 2), q0);
            p0 = pk_fma_h(wh2h[3], HS(h2a, 3), p0);
            q0 = pk_fma_h(wh2h[7], HS(h2b, 3), q0);
            const v2h hc2 = pk_add_h(p0, q0);

            // ---- layer-1 preact: x-dot (f32 acc) + wh1 . h1(t-1) (f16) ----
            const v4h* xr4 = (const v4h*)(xbuf + t2 * ROW_PAD);
            const v4h x0 = xr4[0], x1 = xr4[1], x2 = xr4[2];
            float a1 = bb1, b1 = 0.f;
            a1 = fdot2(wi1h[0], (v2h){x0[0], x0[1]}, a1);
            b1 = fdot2(wi1h[1], (v2h){x0[2], x0[3]}, b1);
            a1 = fdot2(wi1h[2], (v2h){x1[0], x1[1]}, a1);
            b1 = fdot2(wi1h[3], (v2h){x1[2], x1[3]}, b1);
            a1 = fdot2(wi1h[4], (v2h){x2[0], x2[1]}, a1);
            b1 = fdot2(wi1h[5], (v2h){x2[2], x2[3]}, b1);

            v2h u0 = pk_fma_h(wh1h[0], HS(h1a, 0), z2);
            v2h u1 = pk_fma_h(wh1h[4], HS(h1b, 0), z2);
            u0 = pk_fma_h(wh1h[1], HS(h1a, 1), u0);
            u1 = pk_fma_h(wh1h[5], HS(h1b, 1), u1);
            u0 = pk_fma_h(wh1h[2], HS(h1a, 2), u0);
            u1 = pk_fma_h(wh1h[6], HS(h1b, 2), u1);
            u0 = pk_fma_h(wh1h[3], HS(h1a, 3), u0);
            u1 = pk_fma_h(wh1h[7], HS(h1b, 3), u1);
            const float g1 = fdot2(ones, pk_add_h(u0, u1), a1 + b1);

            // ---- layer 1 activation + cell (c1 carried as -2L*c) ----
            const float act1 = __builtin_fmaf(vAa,
                __builtin_amdgcn_rcpf(1.0f + __builtin_amdgcn_exp2f(g1)), vBc);
            {
                const float gi = qperm<0x00>(act1);
                const float gf = qperm<0x55>(act1);
                const float gg = qperm<0xAA>(act1);   // = -2L*tanh(g)
                const float go = qperm<0xFF>(act1);
                c1 = __builtin_fmaf(gf, c1, gi * gg);
                const float tc = __builtin_fmaf(2.0f,
                    __builtin_amdgcn_rcpf(1.0f + __builtin_amdgcn_exp2f(c1)),
                    -1.0f);
                h1w[r] = (_Float16)(go * tc);         // quad-replicated write
            }
            h1a = ((const v8h*)h1w)[0];
            h1b = ((const v8h*)h1w)[1];

            // ---- wi2 . h1(t) (f16 chains) + combine -> g2 ----
            v2h v0 = pk_fma_h(wi2h[0], HS(h1a, 0), z2);
            v2h v1 = pk_fma_h(wi2h[4], HS(h1b, 0), z2);
            v0 = pk_fma_h(wi2h[1], HS(h1a, 1), v0);
            v1 = pk_fma_h(wi2h[5], HS(h1b, 1), v1);
            v0 = pk_fma_h(wi2h[2], HS(h1a, 2), v0);
            v1 = pk_fma_h(wi2h[6], HS(h1b, 2), v1);
            v0 = pk_fma_h(wi2h[3], HS(h1a, 3), v0);
            v1 = pk_fma_h(wi2h[7], HS(h1b, 3), v1);
            const float g2 = fdot2(ones,
                pk_add_h(hc2, pk_add_h(v0, v1)), bb2);

            // ---- layer 2 activation + cell ----
            const float act2 = __builtin_fmaf(vAa,
                __builtin_amdgcn_rcpf(1.0f + __builtin_amdgcn_exp2f(g2)), vBc);
            {
                const float gi = qperm<0x00>(act2);
                const float gf = qperm<0x55>(act2);
                const float gg = qperm<0xAA>(act2);
                const float go = qperm<0xFF>(act2);
                c2 = __builtin_fmaf(gf, c2, gi * gg);
                const float tc = __builtin_fmaf(2.0f,
                    __builtin_amdgcn_rcpf(1.0f + __builtin_amdgcn_exp2f(c2)),
                    -1.0f);
                h2v = go * tc;                        // quad-replicated
                h2w[r] = (_Float16)h2v;
            }
            h2a = ((const v8h*)h2w)[0];
            h2b = ((const v8h*)h2w)[1];

            ssum += __builtin_amdgcn_exp2f(LOG2E * h2v);
        }
    }

    // s[b,k] = exp(h2[T-1,k]) / sum_t exp(h2[t,k]); h2v replicated per quad.
    const float sv = __builtin_amdgcn_exp2f(LOG2E * h2v) / ssum;

    float ssb[H_DIM];
    #pragma unroll
    for (int k = 0; k < H_DIM; ++k) ssb[k] = bcast_lane(sv, 4 * k);

    // Dense head 16 -> 8 -> 8 -> 3 + softmax (one-time epilogue, fp32).
    const int r8 = lane & 7;
    float acc1 = bd1[r8];
    #pragma unroll
    for (int k = 0; k < H_DIM; ++k)
        acc1 = __builtin_fmaf(Wd1[r8 * H_DIM + k], ssb[k], acc1);

    float d1s[8];
    #pragma unroll
    for (int j = 0; j < 8; ++j) d1s[j] = bcast_lane(acc1, j);

    float acc2 = bd2[r8];
    #pragma unroll
    for (int k = 0; k < 8; ++k)
        acc2 = __builtin_fmaf(Wd2[r8 * 8 + k], d1s[k], acc2);

    float d2s[8];
    #pragma unroll
    for (int j = 0; j < 8; ++j) d2s[j] = bcast_lane(acc2, j);

    float lg = 0.f;
    if (lane < 3) {
        lg = bd3[lane];
        #pragma unroll
        for (int k = 0; k < 8; ++k)
            lg = __builtin_fmaf(Wd3[lane * 8 + k], d2s[k], lg);
    }
    const float l0 = bcast_lane(lg, 0);
    const float l1 = bcast_lane(lg, 1);
    const float l2 = bcast_lane(lg, 2);
    const float mx = fmaxf(l0, fmaxf(l1, l2));
    const float e0 = __builtin_amdgcn_exp2f(LOG2E * (l0 - mx));
    const float e1 = __builtin_amdgcn_exp2f(LOG2E * (l1 - mx));
    const float e2 = __builtin_amdgcn_exp2f(LOG2E * (l2 - mx));
    const float inv = 1.0f / (e0 + e1 + e2);
    if (lane < 3) {
        const float ev = (lane == 0) ? e0 : ((lane == 1) ? e1 : e2);
        out[b * 3 + lane] = ev * inv;
    }
}

extern "C" void kernel_launch(void* const* d_in, const int* in_sizes, int n_in,
                              void* d_out, int out_size, void* d_ws, size_t ws_size,
                              hipStream_t stream) {
    (void)in_sizes; (void)n_in; (void)out_size; (void)d_ws; (void)ws_size;
    const float* x    = (const float*)d_in[0];
    const float* Wih1 = (const float*)d_in[1];
    const float* Whh1 = (const float*)d_in[2];
    const float* bih1 = (const float*)d_in[3];
    const float* bhh1 = (const float*)d_in[4];
    const float* Wih2 = (const float*)d_in[5];
    const float* Whh2 = (const float*)d_in[6];
    const float* bih2 = (const float*)d_in[7];
    const float* bhh2 = (const float*)d_in[8];
    const float* Wd1  = (const float*)d_in[9];
    const float* bd1  = (const float*)d_in[10];
    const float* Wd2  = (const float*)d_in[11];
    const float* bd2  = (const float*)d_in[12];
    const float* Wd3  = (const float*)d_in[13];
    const float* bd3  = (const float*)d_in[14];

    lstm2_head<<<dim3(4096 / 4), dim3(256), 0, stream>>>(
        x, Wih1, Whh1, bih1, bhh1, Wih2, Whh2, bih2, bhh2,
        Wd1, bd1, Wd2, bd2, Wd3, bd3, (float*)d_out);
}